// Round 3
// baseline (172.070 us; speedup 1.0000x reference)
//
#include <hip/hip_runtime.h>
#include <hip/hip_cooperative_groups.h>
#include <math.h>

namespace cg = cooperative_groups;

#define H 256
#define W 256
#define TS 16

#if __has_builtin(__builtin_amdgcn_alignbyte)
__device__ __forceinline__ unsigned align_b(unsigned hi, unsigned lo, int sh) {
    return __builtin_amdgcn_alignbyte(hi, lo, sh);
}
#else
__device__ __forceinline__ unsigned align_b(unsigned hi, unsigned lo, int sh) {
    unsigned d;
    asm("v_alignbyte_b32 %0, %1, %2, %3" : "=v"(d) : "v"(hi), "v"(lo), "v"(sh));
    return d;
}
#endif

#if __has_builtin(__builtin_amdgcn_sad_u8)
__device__ __forceinline__ unsigned sad_u8(unsigned a, unsigned b, unsigned acc) {
    return __builtin_amdgcn_sad_u8(a, b, acc);
}
#else
__device__ __forceinline__ unsigned sad_u8(unsigned a, unsigned b, unsigned acc) {
    unsigned d;
    asm("v_sad_u8 %0, %1, %2, %3" : "=v"(d) : "v"(a), "v"(b), "v"(acc));
    return d;
}
#endif

// Single cooperative kernel: phase 1 binomial+quantize, phase 2 SAD search +
// subpixel, phase 3 median+bilateral. grid.sync() between phases (256 blocks
// on 256 CUs -> co-resident).
__global__ void __launch_bounds__(256)
k_fused(const float* __restrict__ f, const float* __restrict__ g,
        float* __restrict__ fb, unsigned char* __restrict__ fq,
        unsigned char* __restrict__ gq, float* __restrict__ flow1,
        float* __restrict__ out) {
    __shared__ union {
        struct {                       // phase 2
            unsigned sfq[26 * 7];      // fq rows [-5,+20], 28 byte cols
            unsigned sgq[20 * 5];      // gq rows [-2,+17], 20 byte cols
            float    sfb[22 * 22];     // fb [-3,+18], replicate pad
        } p2;
        struct {                       // phase 3
            float sfl[2 * 22 * 22];    // flow1, replicate-clamped, tile+3
            float smed[2 * 20 * 20];   // median, 0 for OOB, tile+2
            float sfbt[20 * 20];       // fb, 0 for OOB, tile+2
        } p3;
    } sh;

    cg::grid_group grid = cg::this_grid();

    int tx = threadIdx.x, ty = threadIdx.y;
    int bx0 = blockIdx.x * TS, by0 = blockIdx.y * TS;
    int tid = ty * TS + tx;
    int x = bx0 + tx, y = by0 + ty;

    // ---------------- Phase 1: binomial blur + quantize ----------------
    {
        int ym = max(y - 1, 0), yp = min(y + 1, H - 1);
        int xm = max(x - 1, 0), xp = min(x + 1, W - 1);

        float fvm = (f[ym*W+xm] + 2.0f*f[y*W+xm] + f[yp*W+xm]) * 0.25f;
        float fv0 = (f[ym*W+x ] + 2.0f*f[y*W+x ] + f[yp*W+x ]) * 0.25f;
        float fvp = (f[ym*W+xp] + 2.0f*f[y*W+xp] + f[yp*W+xp]) * 0.25f;
        float fbv = (fvm + 2.0f*fv0 + fvp) * 0.25f;

        float gvm = (g[ym*W+xm] + 2.0f*g[y*W+xm] + g[yp*W+xm]) * 0.25f;
        float gv0 = (g[ym*W+x ] + 2.0f*g[y*W+x ] + g[yp*W+x ]) * 0.25f;
        float gvp = (g[ym*W+xp] + 2.0f*g[y*W+xp] + g[yp*W+xp]) * 0.25f;
        float gbv = (gvm + 2.0f*gv0 + gvp) * 0.25f;

        fb[y*W+x] = fbv;
        fq[y*W+x] = (unsigned char)fminf(fmaxf(rintf(fbv * 255.0f), 0.0f), 255.0f);
        gq[y*W+x] = (unsigned char)fminf(fmaxf(rintf(gbv * 255.0f), 0.0f), 255.0f);
    }
    __threadfence();
    grid.sync();

    // ---------------- Phase 2: SAD search + subpixel ----------------
    {
        unsigned char* sfq_b = (unsigned char*)sh.p2.sfq;
        unsigned char* sgq_b = (unsigned char*)sh.p2.sgq;

        for (int i = tid; i < 26 * 28; i += 256) {
            int r = i / 28, c = i % 28;
            int gy = by0 + r - 5, gx = bx0 + c - 5;
            sfq_b[i] = (gy >= 0 && gy < H && gx >= 0 && gx < W) ? fq[gy*W+gx] : 0;
        }
        for (int i = tid; i < 20 * 20; i += 256) {
            int r = i / 20, c = i % 20;
            int gy = by0 + r - 2, gx = bx0 + c - 2;
            sgq_b[r * 20 + c] = (gy >= 0 && gy < H && gx >= 0 && gx < W) ? gq[gy*W+gx] : 0;
        }
        for (int i = tid; i < 22 * 22; i += 256) {
            int r = i / 22, c = i % 22;
            int gy = min(max(by0 + r - 3, 0), H - 1);
            int gx = min(max(bx0 + c - 3, 0), W - 1);
            sh.p2.sfb[i] = fb[gy*W+gx];
        }
        __syncthreads();

        int base = tx >> 2, a = tx & 3;

        // Per-thread fq window: byte j of w[r] = fq[y-5+r][x-5+j].
        unsigned w0[11], w1[11], w2[11];
        #pragma unroll
        for (int r = 0; r < 11; r++) {
            const unsigned* row = &sh.p2.sfq[(ty + r) * 7 + base];
            unsigned d0 = row[0], d1 = row[1], d2 = row[2], d3 = row[3];
            w0[r] = align_b(d1, d0, a);
            w1[r] = align_b(d2, d1, a);
            w2[r] = align_b(d3, d2, a);
        }

        // g template: row kh -> gq[y-2+kh][x-2 .. x+2]: 4 bytes + 1 byte
        unsigned gt_lo[5], gt_hi[5];
        #pragma unroll
        for (int r = 0; r < 5; r++) {
            const unsigned* row = &sh.p2.sgq[(ty + r) * 5 + base];
            unsigned d0 = row[0], d1 = row[1];
            gt_lo[r] = align_b(d1, d0, a);
            gt_hi[r] = (d1 >> (8 * a)) & 0xFFu;
        }

        const unsigned RANKC[49] = {
            42,43,44,45,46,47,48,
            41,20,21,22,23,24,25,
            40,19, 6, 7, 8, 9,26,
            39,18, 5, 0, 1,10,27,
            38,17, 4, 3, 2,11,28,
            37,16,15,14,13,12,29,
            36,35,34,33,32,31,30
        };

        unsigned best = 0xFFFFFFFFu;
        int bestd = 0;
        #pragma unroll
        for (int si = 0; si < 7; si++) {
            unsigned fd[11], f5[11];
            #pragma unroll
            for (int r = 0; r < 11; r++) {
                fd[r] = (si < 4) ? align_b(w1[r], w0[r], si) : align_b(w2[r], w1[r], si - 4);
                f5[r] = (si < 4) ? ((w1[r] >> (8 * si)) & 0xFFu)
                                 : ((w2[r] >> (8 * (si - 4))) & 0xFFu);
            }
            #pragma unroll
            for (int sj = 0; sj < 7; sj++) {
                unsigned acc0 = 0, acc1 = 0;
                #pragma unroll
                for (int kh = 0; kh < 5; kh++) {
                    acc0 = sad_u8(fd[sj + kh], gt_lo[kh], acc0);
                    acc1 = sad_u8(f5[sj + kh], gt_hi[kh], acc1);
                }
                unsigned score = ((acc0 + acc1) << 6) + RANKC[sj * 7 + si];
                if (score < best) { best = score; bestd = sj * 7 + si; }
            }
        }
        int dy = bestd / 7 - 3, dx = bestd % 7 - 3;

        // Subpixel on the 16-tap template ring (pred mask); OOB taps vanish
        // because every term carries the zero-padded gradient factor.
        float aA = 0.f, bB = 0.f, dD = 0.f, pP = 0.f, qQ = 0.f;
        #pragma unroll
        for (int kh = 0; kh < 5; kh++) {
            #pragma unroll
            for (int kw = 0; kw < 5; kw++) {
                if (kh != 0 && kh != 4 && kw != 0 && kw != 4) continue;
                int yy = y + kh - 2, xx = x + kw - 2;
                if (yy < 0 || yy >= H || xx < 0 || xx >= W) continue;
                int ry = ty + kh + 1, rx = tx + kw + 1;
                float gxv = (sh.p2.sfb[ry*22 + rx+1] - sh.p2.sfb[ry*22 + rx-1]) * 0.5f;
                float gyv = (sh.p2.sfb[(ry+1)*22 + rx] - sh.p2.sfb[(ry-1)*22 + rx]) * 0.5f;
                float fv = (float)sfq_b[(ty + dy + kh + 3) * 28 + (tx + dx + kw + 3)] * (1.0f/255.0f);
                float gv = (float)((kw < 4) ? ((gt_lo[kh] >> (8*kw)) & 0xFFu) : gt_hi[kh]) * (1.0f/255.0f);
                float z = gv - fv;
                aA += gxv * gxv;
                bB += gxv * gyv;
                dD += gyv * gyv;
                pP += z * gxv;
                qQ += z * gyv;
            }
        }
        float det = aA * dD - bB * bB;
        float u = dD * pP - bB * qQ;     // x
        float v = aA * qQ - bB * pP;     // y
        float suby = 0.f, subx = 0.f;
        if (det > 1e-7f) {
            suby = v / det;
            subx = u / det;
            if (fabsf(suby) >= 1.0f) suby = 0.f;
            if (fabsf(subx) >= 1.0f) subx = 0.f;
        }
        flow1[y*W + x]       = (float)(-dy) + suby;
        flow1[H*W + y*W + x] = (float)(-dx) + subx;
    }
    __threadfence();
    grid.sync();

    // ---------------- Phase 3: median + bilateral ----------------
    {
        for (int i = tid; i < 2 * 22 * 22; i += 256) {
            int c = i / 484, rem = i % 484;
            int r = rem / 22, col = rem % 22;
            int qy = min(max(by0 + r - 3, 0), H - 1);
            int qx = min(max(bx0 + col - 3, 0), W - 1);
            sh.p3.sfl[c * 484 + rem] = flow1[c*H*W + qy*W + qx];
        }
        for (int i = tid; i < 20 * 20; i += 256) {
            int r = i / 20, col = i % 20;
            int yy = by0 + r - 2, xx = bx0 + col - 2;
            sh.p3.sfbt[i] = (yy >= 0 && yy < H && xx >= 0 && xx < W) ? fb[yy*W+xx] : 0.0f;
        }
        __syncthreads();

        for (int i = tid; i < 2 * 20 * 20; i += 256) {
            int c = i / 400, rem = i % 400;
            int r = rem / 20, col = rem % 20;
            int py = by0 + r - 2, px = bx0 + col - 2;
            float m = 0.0f;
            if (py >= 0 && py < H && px >= 0 && px < W) {
                float v[9];
                int n = 0;
                #pragma unroll
                for (int j = 0; j < 3; j++)
                    #pragma unroll
                    for (int ii = 0; ii < 3; ii++)
                        v[n++] = sh.p3.sfl[c * 484 + (r + j) * 22 + (col + ii)];
#define MSWAP(A, B) { float t_ = fminf(v[A], v[B]); v[B] = fmaxf(v[A], v[B]); v[A] = t_; }
                MSWAP(1,2); MSWAP(4,5); MSWAP(7,8);
                MSWAP(0,1); MSWAP(3,4); MSWAP(6,7);
                MSWAP(1,2); MSWAP(4,5); MSWAP(7,8);
                MSWAP(0,3); MSWAP(5,8); MSWAP(4,7);
                MSWAP(3,6); MSWAP(1,4); MSWAP(2,5);
                MSWAP(4,7); MSWAP(4,2); MSWAP(6,4);
                MSWAP(4,2);
#undef MSWAP
                m = v[4];
            }
            sh.p3.smed[c * 400 + rem] = m;
        }
        __syncthreads();

        const float kern = -0.22222222222222221f;   // -1/(2*1.5^2)
        const float sii  = 200.0f;                  // 1/(2*0.05^2)
        float cp = sh.p3.sfbt[(ty + 2) * 20 + (tx + 2)];
        float sc = 0.f, sy = 0.f, sx = 0.f;
        #pragma unroll
        for (int j = 0; j < 5; j++) {
            #pragma unroll
            for (int i = 0; i < 5; i++) {
                int s = (ty + j) * 20 + (tx + i);
                float ck = sh.p3.sfbt[s];
                float df = cp - ck;
                float coeff = 1.0f - fabsf(kern - df * df * sii);
                coeff = fminf(fmaxf(coeff, 0.0f), 1.0f);
                sc += coeff;
                sy += coeff * sh.p3.smed[0 * 400 + s];
                sx += coeff * sh.p3.smed[1 * 400 + s];
            }
        }
        out[y*W + x]       = sy / sc;
        out[H*W + y*W + x] = sx / sc;
    }
}

extern "C" void kernel_launch(void* const* d_in, const int* in_sizes, int n_in,
                              void* d_out, int out_size, void* d_ws, size_t ws_size,
                              hipStream_t stream) {
    const float* f = (const float*)d_in[0];
    const float* g = (const float*)d_in[1];
    float* out = (float*)d_out;

    char* ws = (char*)d_ws;
    float*         fb    = (float*)(ws);                    // 256 KiB
    unsigned char* fq    = (unsigned char*)(ws + 262144);   //  64 KiB
    unsigned char* gq    = (unsigned char*)(ws + 327680);   //  64 KiB
    float*         flow1 = (float*)(ws + 393216);           // 512 KiB

    void* args[] = { (void*)&f, (void*)&g, (void*)&fb, (void*)&fq,
                     (void*)&gq, (void*)&flow1, (void*)&out };
    hipLaunchCooperativeKernel((void*)k_fused, dim3(W / TS, H / TS), dim3(TS, TS),
                               args, 0, stream);
}

// Round 4
// 70.080 us; speedup vs baseline: 2.4553x; 2.4553x over previous
//
#include <hip/hip_runtime.h>
#include <math.h>

#define H 256
#define W 256
#define TS 16

#if __has_builtin(__builtin_amdgcn_alignbyte)
__device__ __forceinline__ unsigned align_b(unsigned hi, unsigned lo, int sh) {
    return __builtin_amdgcn_alignbyte(hi, lo, sh);
}
#else
__device__ __forceinline__ unsigned align_b(unsigned hi, unsigned lo, int sh) {
    unsigned d;
    asm("v_alignbyte_b32 %0, %1, %2, %3" : "=v"(d) : "v"(hi), "v"(lo), "v"(sh));
    return d;
}
#endif

#if __has_builtin(__builtin_amdgcn_sad_u8)
__device__ __forceinline__ unsigned sad_u8(unsigned a, unsigned b, unsigned acc) {
    return __builtin_amdgcn_sad_u8(a, b, acc);
}
#else
__device__ __forceinline__ unsigned sad_u8(unsigned a, unsigned b, unsigned acc) {
    unsigned d;
    asm("v_sad_u8 %0, %1, %2, %3" : "=v"(d) : "v"(a), "v"(b), "v"(acc));
    return d;
}
#endif

// Binomial 3x3 at center (r,c) of LDS tile s (stride given). Bitwise identical
// to reference: vertical [1 2 1]/4 per column, then horizontal [1 2 1]/4.
// All scalings are powers of two (exact); addition order matches jnp.
__device__ __forceinline__ float blur9(const float* s, int stride, int r, int c) {
    const float* p0 = s + (r - 1) * stride + c;
    const float* p1 = s + r * stride + c;
    const float* p2 = s + (r + 1) * stride + c;
    float vm = (p0[-1] + 2.0f * p1[-1] + p2[-1]) * 0.25f;
    float v0 = (p0[0]  + 2.0f * p1[0]  + p2[0] ) * 0.25f;
    float vp = (p0[1]  + 2.0f * p1[1]  + p2[1] ) * 0.25f;
    return (vm + 2.0f * v0 + vp) * 0.25f;
}

__device__ __forceinline__ unsigned char quant255(float b) {
    return (unsigned char)fminf(fmaxf(rintf(b * 255.0f), 0.0f), 255.0f);
}

// One kernel, no grid sync, no global intermediates. Per 16x16 tile:
//   A: load f[-9,+24] and g[-6,+21] (position-clamped) into LDS; recompute
//      binomial blur to build fq[-8,+23] (zero at image OOB, byte-packed),
//      gq[-5,+20] (zero OOB, byte-packed), fb[-6,+21] (position-clamped).
//   B: SAD search (v_sad_u8, register windows) + LK subpixel at ALL 22x22
//      positions [-3,+18] -> flow in LDS.
//   C: 3x3 median (replicate-clamped positions) at [-2,+17] -> LDS.
//   D: 5x5 bilateral (zero-padded) -> out.
__global__ void __launch_bounds__(256)
k_all(const float* __restrict__ f, const float* __restrict__ g,
      float* __restrict__ out) {
    __shared__ struct {
        union {
            struct { float sf[34 * 34]; float sg[28 * 28]; } a;          // phase A
            struct { float sflow[2][22 * 22]; float smed[2][20 * 20]; } b; // C/D
        } u;
        unsigned sfq[32 * 9];   // fq rows [-8,+23], 36 byte cols (-8..+27; 32.. zero)
        unsigned sgq[26 * 7];   // gq rows [-5,+20], 28 byte cols (-5..+22; 26.. zero)
        float    sfb[28 * 28];  // fb [-6,+21], position-clamped (replicate)
    } sh;

    int tx = threadIdx.x, ty = threadIdx.y;
    int bx0 = blockIdx.x * TS, by0 = blockIdx.y * TS;
    int tid = ty * TS + tx;
    int x = bx0 + tx, y = by0 + ty;

    unsigned char* sfq_b = (unsigned char*)sh.sfq;
    unsigned char* sgq_b = (unsigned char*)sh.sgq;

    // ---- Phase A: stage f/g (replicate-clamped reads), recompute blur ----
    for (int i = tid; i < 34 * 34; i += 256) {
        int r = i / 34, c = i % 34;
        int gy = min(max(by0 + r - 9, 0), H - 1);
        int gx = min(max(bx0 + c - 9, 0), W - 1);
        sh.u.a.sf[i] = f[gy * W + gx];
    }
    for (int i = tid; i < 28 * 28; i += 256) {
        int r = i / 28, c = i % 28;
        int gy = min(max(by0 + r - 6, 0), H - 1);
        int gx = min(max(bx0 + c - 6, 0), W - 1);
        sh.u.a.sg[i] = g[gy * W + gx];
    }
    __syncthreads();

    for (int i = tid; i < 32 * 36; i += 256) {
        int r = i / 36, c = i % 36;
        int gy = by0 + r - 8, gx = bx0 + c - 8;
        unsigned char v = 0;
        if (c < 32 && gy >= 0 && gy < H && gx >= 0 && gx < W)
            v = quant255(blur9(sh.u.a.sf, 34, r + 1, c + 1));
        sfq_b[r * 36 + c] = v;
    }
    for (int i = tid; i < 26 * 28; i += 256) {
        int r = i / 28, c = i % 28;
        int gy = by0 + r - 5, gx = bx0 + c - 5;
        unsigned char v = 0;
        if (c < 26 && gy >= 0 && gy < H && gx >= 0 && gx < W)
            v = quant255(blur9(sh.u.a.sg, 28, r + 1, c + 1));
        sgq_b[r * 28 + c] = v;
    }
    for (int i = tid; i < 28 * 28; i += 256) {
        int r = i / 28, c = i % 28;
        int cy = min(max(by0 + r - 6, 0), H - 1);   // position-level clamp (edge pad)
        int cx = min(max(bx0 + c - 6, 0), W - 1);
        sh.sfb[i] = blur9(sh.u.a.sf, 34, cy - by0 + 9, cx - bx0 + 9);
    }
    __syncthreads();   // also: last read of u.a before u.b overlay in phase B

    // ---- Phase B: SAD search + subpixel at 22x22 positions ----
    #pragma unroll 1
    for (int pi = tid; pi < 22 * 22; pi += 256) {
        int pr = pi / 22, pc = pi % 22;
        int py0 = by0 + pr - 3, px0 = bx0 + pc - 3;
        bool live = (py0 >= 0 && py0 < H && px0 >= 0 && px0 < W);
        float fy = 0.f, fx = 0.f;
        if (live) {
            int base = pc >> 2, a = pc & 3;

            // window: byte j of w[r] = fq[py0-5+r][px0-5+j]
            unsigned w0[11], w1[11], w2[11];
            #pragma unroll
            for (int r = 0; r < 11; r++) {
                const unsigned* row = &sh.sfq[(pr + r) * 9 + base];
                unsigned d0 = row[0], d1 = row[1], d2 = row[2], d3 = row[3];
                w0[r] = align_b(d1, d0, a);
                w1[r] = align_b(d2, d1, a);
                w2[r] = align_b(d3, d2, a);
            }
            unsigned gt_lo[5], gt_hi[5];
            #pragma unroll
            for (int r = 0; r < 5; r++) {
                const unsigned* row = &sh.sgq[(pr + r) * 7 + base];
                unsigned d0 = row[0], d1 = row[1];
                gt_lo[r] = align_b(d1, d0, a);
                gt_hi[r] = (d1 >> (8 * a)) & 0xFFu;
            }

            const unsigned RANKC[49] = {
                42,43,44,45,46,47,48,
                41,20,21,22,23,24,25,
                40,19, 6, 7, 8, 9,26,
                39,18, 5, 0, 1,10,27,
                38,17, 4, 3, 2,11,28,
                37,16,15,14,13,12,29,
                36,35,34,33,32,31,30
            };

            unsigned best = 0xFFFFFFFFu;
            int bestd = 0;
            #pragma unroll
            for (int si = 0; si < 7; si++) {
                unsigned fd[11], f5[11];
                #pragma unroll
                for (int r = 0; r < 11; r++) {
                    fd[r] = (si < 4) ? align_b(w1[r], w0[r], si) : align_b(w2[r], w1[r], si - 4);
                    f5[r] = (si < 4) ? ((w1[r] >> (8 * si)) & 0xFFu)
                                     : ((w2[r] >> (8 * (si - 4))) & 0xFFu);
                }
                #pragma unroll
                for (int sj = 0; sj < 7; sj++) {
                    unsigned acc0 = 0, acc1 = 0;
                    #pragma unroll
                    for (int kh = 0; kh < 5; kh++) {
                        acc0 = sad_u8(fd[sj + kh], gt_lo[kh], acc0);
                        acc1 = sad_u8(f5[sj + kh], gt_hi[kh], acc1);
                    }
                    unsigned score = ((acc0 + acc1) << 6) + RANKC[sj * 7 + si];
                    if (score < best) { best = score; bestd = sj * 7 + si; }
                }
            }
            int dy = bestd / 7 - 3, dx = bestd % 7 - 3;

            // LK subpixel on the 16-tap ring; OOB taps vanish (zero gradient pad)
            float aA = 0.f, bB = 0.f, dD = 0.f, pP = 0.f, qQ = 0.f;
            #pragma unroll
            for (int kh = 0; kh < 5; kh++) {
                #pragma unroll
                for (int kw = 0; kw < 5; kw++) {
                    if (kh != 0 && kh != 4 && kw != 0 && kw != 4) continue;
                    int yy = py0 + kh - 2, xx = px0 + kw - 2;
                    if (yy < 0 || yy >= H || xx < 0 || xx >= W) continue;
                    int ry = pr + kh + 1, rx = pc + kw + 1;   // sfb coords (origin -6)
                    float gxv = (sh.sfb[ry*28 + rx+1] - sh.sfb[ry*28 + rx-1]) * 0.5f;
                    float gyv = (sh.sfb[(ry+1)*28 + rx] - sh.sfb[(ry-1)*28 + rx]) * 0.5f;
                    float fv = (float)sfq_b[(pr + dy + kh + 3) * 36 + (pc + dx + kw + 3)] * (1.0f/255.0f);
                    float gv = (float)((kw < 4) ? ((gt_lo[kh] >> (8*kw)) & 0xFFu) : gt_hi[kh]) * (1.0f/255.0f);
                    float z = gv - fv;
                    aA += gxv * gxv;
                    bB += gxv * gyv;
                    dD += gyv * gyv;
                    pP += z * gxv;
                    qQ += z * gyv;
                }
            }
            float det = aA * dD - bB * bB;
            float u = dD * pP - bB * qQ;     // x
            float v = aA * qQ - bB * pP;     // y
            float suby = 0.f, subx = 0.f;
            if (det > 1e-7f) {
                suby = v / det;
                subx = u / det;
                if (fabsf(suby) >= 1.0f) suby = 0.f;
                if (fabsf(subx) >= 1.0f) subx = 0.f;
            }
            fy = (float)(-dy) + suby;
            fx = (float)(-dx) + subx;
        }
        sh.u.b.sflow[0][pi] = fy;
        sh.u.b.sflow[1][pi] = fx;
    }
    __syncthreads();

    // ---- Phase C: 3x3 median (replicate-clamped positions) at [-2,+17] ----
    for (int i = tid; i < 2 * 20 * 20; i += 256) {
        int c = i / 400, rem = i % 400;
        int r = rem / 20, col = rem % 20;
        int qy = by0 + r - 2, qx = bx0 + col - 2;
        float m = 0.0f;
        if (qy >= 0 && qy < H && qx >= 0 && qx < W) {
            float v[9];
            int n = 0;
            #pragma unroll
            for (int j = -1; j <= 1; j++)
                #pragma unroll
                for (int ii = -1; ii <= 1; ii++) {
                    int yy = min(max(qy + j, 0), H - 1) - by0 + 3;
                    int xx = min(max(qx + ii, 0), W - 1) - bx0 + 3;
                    v[n++] = sh.u.b.sflow[c][yy * 22 + xx];
                }
#define MSWAP(A, B) { float t_ = fminf(v[A], v[B]); v[B] = fmaxf(v[A], v[B]); v[A] = t_; }
            MSWAP(1,2); MSWAP(4,5); MSWAP(7,8);
            MSWAP(0,1); MSWAP(3,4); MSWAP(6,7);
            MSWAP(1,2); MSWAP(4,5); MSWAP(7,8);
            MSWAP(0,3); MSWAP(5,8); MSWAP(4,7);
            MSWAP(3,6); MSWAP(1,4); MSWAP(2,5);
            MSWAP(4,7); MSWAP(4,2); MSWAP(6,4);
            MSWAP(4,2);
#undef MSWAP
            m = v[4];
        }
        sh.u.b.smed[c][rem] = m;
    }
    __syncthreads();

    // ---- Phase D: 5x5 bilateral (zero-padded guide + median) ----
    {
        const float kern = -0.22222222222222221f;   // -1/(2*1.5^2)
        const float sii  = 200.0f;                  // 1/(2*0.05^2)
        float cp = sh.sfb[(ty + 6) * 28 + (tx + 6)];
        float sc = 0.f, sy = 0.f, sx = 0.f;
        #pragma unroll
        for (int j = -2; j <= 2; j++) {
            #pragma unroll
            for (int i = -2; i <= 2; i++) {
                int yy = y + j, xx = x + i;
                bool inb = (yy >= 0 && yy < H && xx >= 0 && xx < W);
                float ck = inb ? sh.sfb[(ty + j + 6) * 28 + (tx + i + 6)] : 0.0f;
                float df = cp - ck;
                float coeff = 1.0f - fabsf(kern - df * df * sii);
                coeff = fminf(fmaxf(coeff, 0.0f), 1.0f);
                int s = (ty + j + 2) * 20 + (tx + i + 2);
                sc += coeff;
                sy += coeff * sh.u.b.smed[0][s];
                sx += coeff * sh.u.b.smed[1][s];
            }
        }
        out[y * W + x]         = sy / sc;
        out[H * W + y * W + x] = sx / sc;
    }
}

extern "C" void kernel_launch(void* const* d_in, const int* in_sizes, int n_in,
                              void* d_out, int out_size, void* d_ws, size_t ws_size,
                              hipStream_t stream) {
    const float* f = (const float*)d_in[0];
    const float* g = (const float*)d_in[1];
    float* out = (float*)d_out;
    k_all<<<dim3(W / TS, H / TS), dim3(TS, TS), 0, stream>>>(f, g, out);
}